// Round 5
// baseline (3194.883 us; speedup 1.0000x reference)
//
#include <hip/hip_runtime.h>
#include <math.h>

#define VOCAB 1000
#define EMB   128
#define HID   256
#define G4    1024   // 4*HID
#define BATCH 64
#define SEQT  1024
#define KV    92     // half2 cols in VGPRs  (k in [0,184))
#define KL    36     // half2 cols in LDS    (k in [184,256)), 9 b128 chunks

typedef unsigned int u32;
typedef _Float16 f16;
typedef __attribute__((ext_vector_type(2))) _Float16 h2v;
union H2U { u32 u; h2v h; unsigned short s[2]; };

#if defined(__has_builtin)
# if __has_builtin(__builtin_amdgcn_fdot2)
#  define HAVE_FDOT2 1
# endif
#endif
__device__ __forceinline__ float fdot2_(u32 a, u32 b, float c) {
    H2U ua, ub; ua.u = a; ub.u = b;
#ifdef HAVE_FDOT2
    return __builtin_amdgcn_fdot2(ua.h, ub.h, c, false);   // v_dot2_f32_f16
#else
    return c + (float)ua.h.x * (float)ub.h.x + (float)ua.h.y * (float)ub.h.y;
#endif
}

__device__ __forceinline__ float sigmoidf_(float x) {
    return 1.f / (1.f + __expf(-x));
}
__device__ __forceinline__ float tanhf_(float x) {
    return 1.f - 2.f / (__expf(2.f * x) + 1.f);
}

// ---------------------------------------------------------------------------
// Kernel 1: eproj[v][g] = emb[v] . W_ih[g] + b_ih[g] + b_hh[g]   (fp32, exact)
// ---------------------------------------------------------------------------
__global__ __launch_bounds__(1024) void eproj_kernel(
    const float* __restrict__ emb, const float* __restrict__ W_ih,
    const float* __restrict__ b_ih, const float* __restrict__ b_hh,
    float* __restrict__ eproj)
{
    const int v = blockIdx.x;
    const int g = threadIdx.x;
    __shared__ __align__(16) float x_sh[EMB];
    if (g < EMB / 4) {
        ((float4*)x_sh)[g] = ((const float4*)(emb + (size_t)v * EMB))[g];
    }
    __syncthreads();
    const float4* wrow = (const float4*)(W_ih + (size_t)g * EMB);
    float a0 = 0.f, a1 = 0.f, a2 = 0.f, a3 = 0.f;
#pragma unroll
    for (int e4 = 0; e4 < EMB / 4; e4++) {
        float4 wv = wrow[e4];
        float4 xv = ((const float4*)x_sh)[e4];
        a0 += wv.x * xv.x;
        a1 += wv.y * xv.y;
        a2 += wv.z * xv.z;
        a3 += wv.w * xv.w;
    }
    eproj[(size_t)v * G4 + g] = (a0 + a1) + (a2 + a3) + b_ih[g] + b_hh[g];
}

// ---------------------------------------------------------------------------
// Kernel 2: pack W_hh fp32 -> fp16 half2 into two [chunk][row][4] u32 arrays:
// wvq (cols 0..91, 23 chunks) register part, wlq (cols 92..127, 9 chunks)
// LDS part. [chunk][row][4] makes both global loads and LDS b128 reads
// lane-consecutive (canonical conflict-free float4 pattern). UNCHANGED from
// the 1660us baseline.
// ---------------------------------------------------------------------------
__global__ __launch_bounds__(128) void pack_whh(
    const float* __restrict__ Whh, u32* __restrict__ wvq, u32* __restrict__ wlq)
{
    const int r = blockIdx.x;        // row 0..1023
    const int m = threadIdx.x;       // half2 col 0..127
    H2U u;
    u.h.x = (f16)Whh[(size_t)r * HID + 2 * m];
    u.h.y = (f16)Whh[(size_t)r * HID + 2 * m + 1];
    if (m < KV) {
        wvq[(size_t)(m >> 2) * (G4 * 4) + r * 4 + (m & 3)] = u.u;
    } else {
        const int mm = m - KV;
        wlq[(size_t)(mm >> 2) * (G4 * 4) + r * 4 + (mm & 3)] = u.u;
    }
}

// ---------------------------------------------------------------------------
// Kernel 3: single-CU LSTM, 256 threads (4 waves = 1 wave/SIMD, 512-reg cap;
// m08: no spill through 450 regs) per batch element. Evidence from R0/R3/R4:
// no pipe exceeds ~55% duty -- the kernel is bound by per-step serial
// latency chains, because 184 persistent regs at the 256-reg cap left only
// ~40 temps (2-3 chunks of LDS lookahead). This shape fixes the CAUSE:
// thread u owns ALL FOUR gate rows of unit u (i,f,g,o = rows u, 256+u,
// 512+u, 768+u): 368 persistent regs + ~60 temps <= 450, leaving ~100 regs
// for deep software pipelining of the h-broadcast and tail reads. Bonuses:
//  - epilogue is fully thread-local (no gate bounce, no divergence),
//    ONE barrier per step instead of two;
//  - LDS instrs/CU/step 400 -> 272; VALU stays at the 1024 cy/SIMD floor
//    (4 independent accumulator chains = 4-cy dep fully covered at 2-cy
//    issue);
//  - per-row accumulation order identical to the 1660us kernel ->
//    bit-identical numerics. Zero cross-CU traffic.
// ---------------------------------------------------------------------------
__global__ __launch_bounds__(256, 1) void lstm_single_cu(
    const int* __restrict__ ids, const int* __restrict__ lens,
    const float* __restrict__ eproj,
    const u32* __restrict__ wvq, const u32* __restrict__ wlq,
    float* __restrict__ out)
{
    const int b  = blockIdx.x;
    const int u  = threadIdx.x;                  // 0..255 == unit index
    const int rI = u;                            // gate i row
    const int rF = 256 + u;                      // gate f row
    const int rG = 512 + u;                      // gate g row
    const int rO = 768 + u;                      // gate o row

    __shared__ u32 wl_sh[KL / 4 * G4 * 4];       // 9 chunks x 1024 rows x 16B
    __shared__ u32 h2_sh[2][HID / 2];            // h as half2, parity x2
    __shared__ int id_sh[SEQT];                  // this block's id row (4 KB)

    const int* idr = ids + (size_t)b * SEQT;
    ((int4*)id_sh)[u] = ((const int4*)idr)[u];   // 256 x 16B = 4 KB
    if (u < HID / 2) h2_sh[0][u] = 0u;           // h(0) = 0

    // stage LDS weight tail (b128 both sides, coalesced): 36 iters
    {
        const uint4* src = (const uint4*)wlq;
        uint4*       dst = (uint4*)wl_sh;
#pragma unroll
        for (int t = 0; t < (KL / 4) * G4 / 256; t++)
            dst[t * 256 + u] = src[t * 256 + u];
    }

    // persistent VGPR weights: 4 rows x 92 half2 = 368 regs
    u32 wI[KV], wF[KV], wG[KV], wO[KV];
#pragma unroll
    for (int q = 0; q < KV / 4; q++) {
        uint4 ti = ((const uint4*)wvq)[q * G4 + rI];
        uint4 tf = ((const uint4*)wvq)[q * G4 + rF];
        uint4 tg = ((const uint4*)wvq)[q * G4 + rG];
        uint4 to = ((const uint4*)wvq)[q * G4 + rO];
        wI[4 * q + 0] = ti.x; wI[4 * q + 1] = ti.y;
        wI[4 * q + 2] = ti.z; wI[4 * q + 3] = ti.w;
        wF[4 * q + 0] = tf.x; wF[4 * q + 1] = tf.y;
        wF[4 * q + 2] = tf.z; wF[4 * q + 3] = tf.w;
        wG[4 * q + 0] = tg.x; wG[4 * q + 1] = tg.y;
        wG[4 * q + 2] = tg.z; wG[4 * q + 3] = tg.w;
        wO[4 * q + 0] = to.x; wO[4 * q + 1] = to.y;
        wO[4 * q + 2] = to.z; wO[4 * q + 3] = to.w;
    }

    const int len = lens[b];                     // >= 1
    float c = 0.f, hf = 0.f;

    const float* e0 = eproj + (size_t)idr[0] * G4;
    float xI = e0[rI], xF = e0[rF], xG = e0[rG], xO = e0[rO];

    __syncthreads();

    for (int t = 0; t < len; t++) {
        // prefetch next step's input projections (hidden under dot loops)
        const int nt = (t + 1 < len) ? t + 1 : len - 1;
        const int nid = id_sh[nt];
        const float* en = eproj + (size_t)nid * G4;
        const float nI = en[rI], nF = en[rF], nG = en[rG], nO = en[rO];

        const int p = t & 1;
        const uint4* hb4 = (const uint4*)h2_sh[p];   // 32 b128 broadcasts
        float aI = xI, aF = xF, aG = xG, aO = xO;

        // register cols 0..91 (23 chunks); 4 independent acc chains
#pragma unroll
        for (int q = 0; q < KV / 4; q++) {
            uint4 h4 = hb4[q];
            aI = fdot2_(wI[4 * q + 0], h4.x, aI);
            aF = fdot2_(wF[4 * q + 0], h4.x, aF);
            aG = fdot2_(wG[4 * q + 0], h4.x, aG);
            aO = fdot2_(wO[4 * q + 0], h4.x, aO);
            aI = fdot2_(wI[4 * q + 1], h4.y, aI);
            aF = fdot2_(wF[4 * q + 1], h4.y, aF);
            aG = fdot2_(wG[4 * q + 1], h4.y, aG);
            aO = fdot2_(wO[4 * q + 1], h4.y, aO);
            aI = fdot2_(wI[4 * q + 2], h4.z, aI);
            aF = fdot2_(wF[4 * q + 2], h4.z, aF);
            aG = fdot2_(wG[4 * q + 2], h4.z, aG);
            aO = fdot2_(wO[4 * q + 2], h4.z, aO);
            aI = fdot2_(wI[4 * q + 3], h4.w, aI);
            aF = fdot2_(wF[4 * q + 3], h4.w, aF);
            aG = fdot2_(wG[4 * q + 3], h4.w, aG);
            aO = fdot2_(wO[4 * q + 3], h4.w, aO);
        }
        // LDS tail cols 92..127 (lane-consecutive b128, conflict-free)
#pragma unroll
        for (int q = 0; q < KL / 4; q++) {
            uint4 h4 = hb4[KV / 4 + q];
            uint4 tI = ((const uint4*)wl_sh)[q * G4 + rI];
            uint4 tF = ((const uint4*)wl_sh)[q * G4 + rF];
            uint4 tG = ((const uint4*)wl_sh)[q * G4 + rG];
            uint4 tO = ((const uint4*)wl_sh)[q * G4 + rO];
            aI = fdot2_(tI.x, h4.x, aI);
            aF = fdot2_(tF.x, h4.x, aF);
            aG = fdot2_(tG.x, h4.x, aG);
            aO = fdot2_(tO.x, h4.x, aO);
            aI = fdot2_(tI.y, h4.y, aI);
            aF = fdot2_(tF.y, h4.y, aF);
            aG = fdot2_(tG.y, h4.y, aG);
            aO = fdot2_(tO.y, h4.y, aO);
            aI = fdot2_(tI.z, h4.z, aI);
            aF = fdot2_(tF.z, h4.z, aF);
            aG = fdot2_(tG.z, h4.z, aG);
            aO = fdot2_(tO.z, h4.z, aO);
            aI = fdot2_(tI.w, h4.w, aI);
            aF = fdot2_(tF.w, h4.w, aF);
            aG = fdot2_(tG.w, h4.w, aG);
            aO = fdot2_(tO.w, h4.w, aO);
        }

        // fully-local epilogue: no bounce, no divergence
        float ig = sigmoidf_(aI);
        float fg = sigmoidf_(aF);
        float gg = tanhf_(aG);
        float og = sigmoidf_(aO);
        c  = fg * c + ig * gg;
        hf = og * tanhf_(c);
        H2U hv; hv.h.x = (f16)hf; hv.h.y = (f16)0.f;
        ((unsigned short*)h2_sh[p ^ 1])[u] = hv.s[0];

        xI = nI; xF = nF; xG = nG; xO = nO;
        __syncthreads();             // ONE barrier/step: h(t+1) published
    }

    out[(size_t)b * HID + u] = hf;
}

// ---------------------------------------------------------------------------
// Fallback (ws too small): correct-but-slow single-block fp32 version.
// ---------------------------------------------------------------------------
__global__ __launch_bounds__(1024, 1) void lstm_fallback(
    const int* __restrict__ ids, const int* __restrict__ lens,
    const float* __restrict__ emb, const float* __restrict__ W_ih,
    const float* __restrict__ b_ih, const float* __restrict__ b_hh,
    const float* __restrict__ W_hh, float* __restrict__ out)
{
    const int b = blockIdx.x;
    const int t = threadIdx.x;

    __shared__ __align__(16) float h_sh[HID];
    __shared__ __align__(16) float c_sh[HID];
    __shared__ __align__(16) float gates[G4];
    __shared__ __align__(16) float x_sh[EMB];

    float wih[EMB];
    {
        const float4* wr = (const float4*)(W_ih + (size_t)t * EMB);
#pragma unroll
        for (int e4 = 0; e4 < EMB / 4; e4++) {
            float4 wv = wr[e4];
            wih[4 * e4 + 0] = wv.x;
            wih[4 * e4 + 1] = wv.y;
            wih[4 * e4 + 2] = wv.z;
            wih[4 * e4 + 3] = wv.w;
        }
    }
    float bias = b_ih[t] + b_hh[t];

    const int len = lens[b];
    const int* ids_row = ids + (size_t)b * SEQT;
    if (t < HID) { h_sh[t] = 0.f; c_sh[t] = 0.f; }
    __syncthreads();

    for (int step = 0; step < len; step++) {
        int id = ids_row[step];
        if (t < EMB / 4) {
            ((float4*)x_sh)[t] = ((const float4*)(emb + (size_t)id * EMB))[t];
        }
        __syncthreads();
        float a0 = bias, a1 = 0.f, a2 = 0.f, a3 = 0.f;
#pragma unroll
        for (int e4 = 0; e4 < EMB / 4; e4++) {
            float4 xv = ((const float4*)x_sh)[e4];
            a0 += wih[4 * e4 + 0] * xv.x;
            a1 += wih[4 * e4 + 1] * xv.y;
            a2 += wih[4 * e4 + 2] * xv.z;
            a3 += wih[4 * e4 + 3] * xv.w;
        }
        float acc = (a0 + a1) + (a2 + a3);

        const float* wrow = W_hh + (size_t)t * HID;
        a0 = acc; a1 = 0.f; a2 = 0.f; a3 = 0.f;
        for (int k4 = 0; k4 < HID / 4; k4++) {
            float4 hv = ((const float4*)h_sh)[k4];
            float4 wv = ((const float4*)wrow)[k4];
            a0 += wv.x * hv.x;
            a1 += wv.y * hv.y;
            a2 += wv.z * hv.z;
            a3 += wv.w * hv.w;
        }
        gates[t] = (a0 + a1) + (a2 + a3);
        __syncthreads();

        if (t < HID) {
            float ig = sigmoidf_(gates[t]);
            float fg = sigmoidf_(gates[HID + t]);
            float gg = tanhf_(gates[2 * HID + t]);
            float og = sigmoidf_(gates[3 * HID + t]);
            float cc = fg * c_sh[t] + ig * gg;
            c_sh[t] = cc;
            h_sh[t] = og * tanhf_(cc);
        }
        __syncthreads();
    }
    if (t < HID) out[(size_t)b * HID + t] = h_sh[t];
}

extern "C" void kernel_launch(void* const* d_in, const int* in_sizes, int n_in,
                              void* d_out, int out_size, void* d_ws, size_t ws_size,
                              hipStream_t stream) {
    const int*   ids  = (const int*)d_in[0];
    const int*   lens = (const int*)d_in[1];
    const float* emb  = (const float*)d_in[2];
    const float* Wih  = (const float*)d_in[3];
    const float* Whh  = (const float*)d_in[4];
    const float* bih  = (const float*)d_in[5];
    const float* bhh  = (const float*)d_in[6];
    float* out = (float*)d_out;

    // ws layout: eproj 4 MB | wvq 368 KB | wlq 144 KB
    const size_t ep_bytes = (size_t)VOCAB * G4 * sizeof(float);
    const size_t wv_off   = ep_bytes;
    const size_t wv_bytes = (size_t)(KV / 4) * G4 * 4 * sizeof(u32);
    const size_t wl_off   = wv_off + wv_bytes;
    const size_t wl_bytes = (size_t)(KL / 4) * G4 * 4 * sizeof(u32);

    if (ws_size >= wl_off + wl_bytes) {
        float* eproj = (float*)d_ws;
        u32*   wvp   = (u32*)((char*)d_ws + wv_off);
        u32*   wlp   = (u32*)((char*)d_ws + wl_off);
        eproj_kernel<<<VOCAB, 1024, 0, stream>>>(emb, Wih, bih, bhh, eproj);
        pack_whh<<<G4, 128, 0, stream>>>(Whh, wvp, wlp);
        lstm_single_cu<<<BATCH, 256, 0, stream>>>(ids, lens, eproj, wvp, wlp, out);
    } else {
        lstm_fallback<<<BATCH, 1024, 0, stream>>>(
            ids, lens, emb, Wih, bih, bhh, Whh, out);
    }
}

// Round 6
// 1914.091 us; speedup vs baseline: 1.6691x; 1.6691x over previous
//
#include <hip/hip_runtime.h>
#include <math.h>

#define VOCAB 1000
#define EMB   128
#define HID   256
#define G4    1024   // 4*HID
#define BATCH 64
#define SEQT  1024
#define KV    108    // half2 cols in VGPR/AGPR (k in [0,216)), 27 chunks
#define KL    20     // half2 cols in LDS (k in [216,256)), 5 b128 chunks

typedef unsigned int u32;
typedef _Float16 f16;
typedef __attribute__((ext_vector_type(2))) _Float16 h2v;
union H2U { u32 u; h2v h; unsigned short s[2]; };

#if defined(__has_builtin)
# if __has_builtin(__builtin_amdgcn_fdot2)
#  define HAVE_FDOT2 1
# endif
#endif
__device__ __forceinline__ float fdot2_(u32 a, u32 b, float c) {
    H2U ua, ub; ua.u = a; ub.u = b;
#ifdef HAVE_FDOT2
    return __builtin_amdgcn_fdot2(ua.h, ub.h, c, false);   // v_dot2_f32_f16
#else
    return c + (float)ua.h.x * (float)ub.h.x + (float)ua.h.y * (float)ub.h.y;
#endif
}

__device__ __forceinline__ float sigmoidf_(float x) {
    return 1.f / (1.f + __expf(-x));
}
__device__ __forceinline__ float tanhf_(float x) {
    return 1.f - 2.f / (__expf(2.f * x) + 1.f);
}

// ---------------------------------------------------------------------------
// Kernel 1: eproj[v][g] = emb[v] . W_ih[g] + b_ih[g] + b_hh[g]   (fp32, exact)
// ---------------------------------------------------------------------------
__global__ __launch_bounds__(1024) void eproj_kernel(
    const float* __restrict__ emb, const float* __restrict__ W_ih,
    const float* __restrict__ b_ih, const float* __restrict__ b_hh,
    float* __restrict__ eproj)
{
    const int v = blockIdx.x;
    const int g = threadIdx.x;
    __shared__ __align__(16) float x_sh[EMB];
    if (g < EMB / 4) {
        ((float4*)x_sh)[g] = ((const float4*)(emb + (size_t)v * EMB))[g];
    }
    __syncthreads();
    const float4* wrow = (const float4*)(W_ih + (size_t)g * EMB);
    float a0 = 0.f, a1 = 0.f, a2 = 0.f, a3 = 0.f;
#pragma unroll
    for (int e4 = 0; e4 < EMB / 4; e4++) {
        float4 wv = wrow[e4];
        float4 xv = ((const float4*)x_sh)[e4];
        a0 += wv.x * xv.x;
        a1 += wv.y * xv.y;
        a2 += wv.z * xv.z;
        a3 += wv.w * xv.w;
    }
    eproj[(size_t)v * G4 + g] = (a0 + a1) + (a2 + a3) + b_ih[g] + b_hh[g];
}

// ---------------------------------------------------------------------------
// Kernel 2: pack W_hh fp32 -> fp16 half2 into two [chunk][row][4] u32 arrays:
// wvq (cols 0..107, 27 chunks) register part, wlq (cols 108..127, 5 chunks)
// LDS part. [chunk][row][4] makes both global loads and LDS b128 reads
// lane-consecutive (canonical conflict-free float4 pattern).
// ---------------------------------------------------------------------------
__global__ __launch_bounds__(128) void pack_whh(
    const float* __restrict__ Whh, u32* __restrict__ wvq, u32* __restrict__ wlq)
{
    const int r = blockIdx.x;        // row 0..1023
    const int m = threadIdx.x;       // half2 col 0..127
    H2U u;
    u.h.x = (f16)Whh[(size_t)r * HID + 2 * m];
    u.h.y = (f16)Whh[(size_t)r * HID + 2 * m + 1];
    if (m < KV) {
        wvq[(size_t)(m >> 2) * (G4 * 4) + r * 4 + (m & 3)] = u.u;
    } else {
        const int mm = m - KV;
        wlq[(size_t)(mm >> 2) * (G4 * 4) + r * 4 + (mm & 3)] = u.u;
    }
}

// ---------------------------------------------------------------------------
// Kernel 3: single-CU LSTM -- the proven 1660us structure (512 thr, 8 waves,
// 2 waves/SIMD) with the LDS weight tail shrunk. Occupancy bracket
// (R3: 4w/SIMD=4750cy, R0: 2w=3880cy, R5: 1w=7200cy) fixes 2w/SIMD; within
// it, step time tracks the LDS pipe: tail (144 lane-spread b128 ~1730cy) +
// h-broadcasts (256 uniform b128 ~1280cy, irreducible) vs 1024cy VALU floor.
// R0's own counters (VGPR=120 holding 184 persistent, WRITE_SIZE=64, VALU
// near floor) prove persistent weights park in AGPRs read directly by
// v_dot2, so the real budget is persist+temps <= 256 unified: KV=108
// (216 persist + ~34 temps) cuts tail LDS instrs 144 -> 80 (~-770cy/step
// on the bottleneck pipe). Gate bounce is pre-activated (serial epilogue
// ~250 -> ~60cy); same float ops, bit-identical numerics.
// ---------------------------------------------------------------------------
__global__ __launch_bounds__(512, 2) void lstm_single_cu(
    const int* __restrict__ ids, const int* __restrict__ lens,
    const float* __restrict__ eproj,
    const u32* __restrict__ wvq, const u32* __restrict__ wlq,
    float* __restrict__ out)
{
    const int b   = blockIdx.x;
    const int tau = threadIdx.x;                 // 0..511
    const int rA  = tau;                         // gate i (tau<256) / f
    const int rB  = 512 + tau;                   // gate g (tau<256) / o

    __shared__ u32   wl_sh[KL / 4 * G4 * 4];     // 5 chunks x 1024 rows x 16B
    __shared__ u32   h2_sh[2][HID / 2];          // h as half2, parity x2
    __shared__ float gs_f[HID], gs_o[HID];       // ACTIVATED f,o bounce
    __shared__ int   id_sh[SEQT];                // this block's id row (4 KB)

    const int* idr = ids + (size_t)b * SEQT;
    ((int2*)id_sh)[tau] = ((const int2*)idr)[tau];   // 512 x 8B = 4 KB
    if (tau < HID / 2) h2_sh[0][tau] = 0u;           // h(0) = 0

    // stage LDS weight tail (b128 both sides, coalesced): 10 iters
    {
        const uint4* src = (const uint4*)wlq;
        uint4*       dst = (uint4*)wl_sh;
#pragma unroll
        for (int t = 0; t < (KL / 4) * G4 / 512; t++)
            dst[t * 512 + tau] = src[t * 512 + tau];
    }

    // persistent weights: 2 rows x 108 half2 = 216 regs (VGPR+AGPR unified)
    u32 wA[KV], wB[KV];
#pragma unroll
    for (int q = 0; q < KV / 4; q++) {
        uint4 ta = ((const uint4*)wvq)[q * G4 + rA];
        uint4 tb = ((const uint4*)wvq)[q * G4 + rB];
        wA[4 * q + 0] = ta.x; wA[4 * q + 1] = ta.y;
        wA[4 * q + 2] = ta.z; wA[4 * q + 3] = ta.w;
        wB[4 * q + 0] = tb.x; wB[4 * q + 1] = tb.y;
        wB[4 * q + 2] = tb.z; wB[4 * q + 3] = tb.w;
    }

    const int len = lens[b];                     // >= 1
    float c = 0.f, hf = 0.f;

    const float* e0 = eproj + (size_t)idr[0] * G4;
    float xA = e0[rA], xB = e0[rB];

    __syncthreads();

    for (int t = 0; t < len; t++) {
        // prefetch next step's input projections (hidden under dot loops)
        const int nt = (t + 1 < len) ? t + 1 : len - 1;
        const int nid = id_sh[nt];
        const float* en = eproj + (size_t)nid * G4;
        const float nA = en[rA], nB = en[rB];

        const int p = t & 1;
        const uint4* hb4 = (const uint4*)h2_sh[p];   // 32 b128 broadcasts
        float aA = xA, aB = xB;

        // register cols 0..107 (27 chunks)
#pragma unroll
        for (int q = 0; q < KV / 4; q++) {
            uint4 h4 = hb4[q];
            aA = fdot2_(wA[4 * q + 0], h4.x, aA);
            aB = fdot2_(wB[4 * q + 0], h4.x, aB);
            aA = fdot2_(wA[4 * q + 1], h4.y, aA);
            aB = fdot2_(wB[4 * q + 1], h4.y, aB);
            aA = fdot2_(wA[4 * q + 2], h4.z, aA);
            aB = fdot2_(wB[4 * q + 2], h4.z, aB);
            aA = fdot2_(wA[4 * q + 3], h4.w, aA);
            aB = fdot2_(wB[4 * q + 3], h4.w, aB);
        }
        // LDS tail cols 108..127 (lane-consecutive b128, conflict-free)
#pragma unroll
        for (int q = 0; q < KL / 4; q++) {
            uint4 h4 = hb4[KV / 4 + q];
            uint4 tA = ((const uint4*)wl_sh)[q * G4 + rA];
            uint4 tB = ((const uint4*)wl_sh)[q * G4 + rB];
            aA = fdot2_(tA.x, h4.x, aA);
            aB = fdot2_(tB.x, h4.x, aB);
            aA = fdot2_(tA.y, h4.y, aA);
            aB = fdot2_(tB.y, h4.y, aB);
            aA = fdot2_(tA.z, h4.z, aA);
            aB = fdot2_(tB.z, h4.z, aB);
            aA = fdot2_(tA.w, h4.w, aA);
            aB = fdot2_(tB.w, h4.w, aB);
        }

        // pre-activate in parallel, then bounce ACTIVATED f,o
        float ig = 0.f, gg = 0.f;
        if (tau >= HID) {            // rows f,o: sigmoid here (parallel)
            gs_f[tau - HID] = sigmoidf_(aA);
            gs_o[tau - HID] = sigmoidf_(aB);
        } else {                     // rows i,g: activate own gates now
            ig = sigmoidf_(aA);
            gg = tanhf_(aB);
        }
        __syncthreads();             // barrier A: activated values visible

        if (tau < HID) {             // unit owner: short serial path
            c  = gs_f[tau] * c + ig * gg;
            hf = gs_o[tau] * tanhf_(c);
            H2U hv; hv.h.x = (f16)hf; hv.h.y = (f16)0.f;
            ((unsigned short*)h2_sh[p ^ 1])[tau] = hv.s[0];
        }
        xA = nA; xB = nB;
        __syncthreads();             // barrier B: h(t+1) published
    }

    if (tau < HID) out[(size_t)b * HID + tau] = hf;
}

// ---------------------------------------------------------------------------
// Fallback (ws too small): correct-but-slow single-block fp32 version.
// ---------------------------------------------------------------------------
__global__ __launch_bounds__(1024, 1) void lstm_fallback(
    const int* __restrict__ ids, const int* __restrict__ lens,
    const float* __restrict__ emb, const float* __restrict__ W_ih,
    const float* __restrict__ b_ih, const float* __restrict__ b_hh,
    const float* __restrict__ W_hh, float* __restrict__ out)
{
    const int b = blockIdx.x;
    const int t = threadIdx.x;

    __shared__ __align__(16) float h_sh[HID];
    __shared__ __align__(16) float c_sh[HID];
    __shared__ __align__(16) float gates[G4];
    __shared__ __align__(16) float x_sh[EMB];

    float wih[EMB];
    {
        const float4* wr = (const float4*)(W_ih + (size_t)t * EMB);
#pragma unroll
        for (int e4 = 0; e4 < EMB / 4; e4++) {
            float4 wv = wr[e4];
            wih[4 * e4 + 0] = wv.x;
            wih[4 * e4 + 1] = wv.y;
            wih[4 * e4 + 2] = wv.z;
            wih[4 * e4 + 3] = wv.w;
        }
    }
    float bias = b_ih[t] + b_hh[t];

    const int len = lens[b];
    const int* ids_row = ids + (size_t)b * SEQT;
    if (t < HID) { h_sh[t] = 0.f; c_sh[t] = 0.f; }
    __syncthreads();

    for (int step = 0; step < len; step++) {
        int id = ids_row[step];
        if (t < EMB / 4) {
            ((float4*)x_sh)[t] = ((const float4*)(emb + (size_t)id * EMB))[t];
        }
        __syncthreads();
        float a0 = bias, a1 = 0.f, a2 = 0.f, a3 = 0.f;
#pragma unroll
        for (int e4 = 0; e4 < EMB / 4; e4++) {
            float4 xv = ((const float4*)x_sh)[e4];
            a0 += wih[4 * e4 + 0] * xv.x;
            a1 += wih[4 * e4 + 1] * xv.y;
            a2 += wih[4 * e4 + 2] * xv.z;
            a3 += wih[4 * e4 + 3] * xv.w;
        }
        float acc = (a0 + a1) + (a2 + a3);

        const float* wrow = W_hh + (size_t)t * HID;
        a0 = acc; a1 = 0.f; a2 = 0.f; a3 = 0.f;
        for (int k4 = 0; k4 < HID / 4; k4++) {
            float4 hv = ((const float4*)h_sh)[k4];
            float4 wv = ((const float4*)wrow)[k4];
            a0 += wv.x * hv.x;
            a1 += wv.y * hv.y;
            a2 += wv.z * hv.z;
            a3 += wv.w * hv.w;
        }
        gates[t] = (a0 + a1) + (a2 + a3);
        __syncthreads();

        if (t < HID) {
            float ig = sigmoidf_(gates[t]);
            float fg = sigmoidf_(gates[HID + t]);
            float gg = tanhf_(gates[2 * HID + t]);
            float og = sigmoidf_(gates[3 * HID + t]);
            float cc = fg * c_sh[t] + ig * gg;
            c_sh[t] = cc;
            h_sh[t] = og * tanhf_(cc);
        }
        __syncthreads();
    }
    if (t < HID) out[(size_t)b * HID + t] = h_sh[t];
}

extern "C" void kernel_launch(void* const* d_in, const int* in_sizes, int n_in,
                              void* d_out, int out_size, void* d_ws, size_t ws_size,
                              hipStream_t stream) {
    const int*   ids  = (const int*)d_in[0];
    const int*   lens = (const int*)d_in[1];
    const float* emb  = (const float*)d_in[2];
    const float* Wih  = (const float*)d_in[3];
    const float* Whh  = (const float*)d_in[4];
    const float* bih  = (const float*)d_in[5];
    const float* bhh  = (const float*)d_in[6];
    float* out = (float*)d_out;

    // ws layout: eproj 4 MB | wvq 432 KB | wlq 80 KB
    const size_t ep_bytes = (size_t)VOCAB * G4 * sizeof(float);
    const size_t wv_off   = ep_bytes;
    const size_t wv_bytes = (size_t)(KV / 4) * G4 * 4 * sizeof(u32);
    const size_t wl_off   = wv_off + wv_bytes;
    const size_t wl_bytes = (size_t)(KL / 4) * G4 * 4 * sizeof(u32);

    if (ws_size >= wl_off + wl_bytes) {
        float* eproj = (float*)d_ws;
        u32*   wvp   = (u32*)((char*)d_ws + wv_off);
        u32*   wlp   = (u32*)((char*)d_ws + wl_off);
        eproj_kernel<<<VOCAB, 1024, 0, stream>>>(emb, Wih, bih, bhh, eproj);
        pack_whh<<<G4, 128, 0, stream>>>(Whh, wvp, wlp);
        lstm_single_cu<<<BATCH, 512, 0, stream>>>(ids, lens, eproj, wvp, wlp, out);
    } else {
        lstm_fallback<<<BATCH, 1024, 0, stream>>>(
            ids, lens, emb, Wih, bih, bhh, Whh, out);
    }
}

// Round 7
// 1618.076 us; speedup vs baseline: 1.9745x; 1.1829x over previous
//
#include <hip/hip_runtime.h>
#include <math.h>

#define VOCAB 1000
#define EMB   128
#define HID   256
#define G4    1024   // 4*HID
#define BATCH 64
#define SEQT  1024
#define KVH   48     // reg h2 cols per k-half (12 chunks)
#define KLH   16     // LDS h2 cols per k-half (4 chunks)

typedef unsigned int u32;
typedef _Float16 f16;
typedef __attribute__((ext_vector_type(2))) _Float16 h2v;
union H2U { u32 u; h2v h; unsigned short s[2]; };

#if defined(__has_builtin)
# if __has_builtin(__builtin_amdgcn_fdot2)
#  define HAVE_FDOT2 1
# endif
#endif
__device__ __forceinline__ float fdot2_(u32 a, u32 b, float c) {
    H2U ua, ub; ua.u = a; ub.u = b;
#ifdef HAVE_FDOT2
    return __builtin_amdgcn_fdot2(ua.h, ub.h, c, false);   // v_dot2_f32_f16
#else
    return c + (float)ua.h.x * (float)ub.h.x + (float)ua.h.y * (float)ub.h.y;
#endif
}

__device__ __forceinline__ float sigmoidf_(float x) {
    return 1.f / (1.f + __expf(-x));
}
__device__ __forceinline__ float tanhf_(float x) {
    return 1.f - 2.f / (__expf(2.f * x) + 1.f);
}

// ---------------------------------------------------------------------------
// Kernel 1: eproj[v][g] = emb[v] . W_ih[g] + b_ih[g] + b_hh[g]   (fp32, exact)
// ---------------------------------------------------------------------------
__global__ __launch_bounds__(1024) void eproj_kernel(
    const float* __restrict__ emb, const float* __restrict__ W_ih,
    const float* __restrict__ b_ih, const float* __restrict__ b_hh,
    float* __restrict__ eproj)
{
    const int v = blockIdx.x;
    const int g = threadIdx.x;
    __shared__ __align__(16) float x_sh[EMB];
    if (g < EMB / 4) {
        ((float4*)x_sh)[g] = ((const float4*)(emb + (size_t)v * EMB))[g];
    }
    __syncthreads();
    const float4* wrow = (const float4*)(W_ih + (size_t)g * EMB);
    float a0 = 0.f, a1 = 0.f, a2 = 0.f, a3 = 0.f;
#pragma unroll
    for (int e4 = 0; e4 < EMB / 4; e4++) {
        float4 wv = wrow[e4];
        float4 xv = ((const float4*)x_sh)[e4];
        a0 += wv.x * xv.x;
        a1 += wv.y * xv.y;
        a2 += wv.z * xv.z;
        a3 += wv.w * xv.w;
    }
    eproj[(size_t)v * G4 + g] = (a0 + a1) + (a2 + a3) + b_ih[g] + b_hh[g];
}

// ---------------------------------------------------------------------------
// Kernel 2: pack W_hh fp32 -> fp16 half2, k-half split layout.
// h2 col m (0..127): half j = m>>6, within-half col mm = m&63.
// mm <  48 -> wvq chunk j*12 + mm/4  (register part, 24 chunks, 384 KB)
// mm >= 48 -> wlq chunk j*4 + (mm-48)/4  (LDS part, 8 chunks, 128 KB)
// [chunk][row][4] keeps global loads and LDS b128 reads lane-consecutive.
// ---------------------------------------------------------------------------
__global__ __launch_bounds__(128) void pack_whh(
    const float* __restrict__ Whh, u32* __restrict__ wvq, u32* __restrict__ wlq)
{
    const int r = blockIdx.x;        // row 0..1023
    const int m = threadIdx.x;       // h2 col 0..127
    H2U u;
    u.h.x = (f16)Whh[(size_t)r * HID + 2 * m];
    u.h.y = (f16)Whh[(size_t)r * HID + 2 * m + 1];
    const int j  = m >> 6;           // k-half
    const int mm = m & 63;
    if (mm < KVH) {
        const int chunk = j * (KVH / 4) + (mm >> 2);
        wvq[(size_t)chunk * (G4 * 4) + r * 4 + (mm & 3)] = u.u;
    } else {
        const int t2 = mm - KVH;
        const int chunk = j * (KLH / 4) + (t2 >> 2);
        wlq[(size_t)chunk * (G4 * 4) + r * 4 + (t2 & 3)] = u.u;
    }
}

// ---------------------------------------------------------------------------
// Kernel 3: single-CU LSTM, k-split. 512 thr (8 waves, 2/SIMD -- the proven
// optimum from the R0/R3/R5 occupancy bracket). R6 disproved LDS-throughput
// binding (fewer LDS instrs -> slower); the regressions correlate with lost
// scheduling temps, i.e. the kernel is LATENCY-chain bound: h ds_read
// exposure + 128-deep fdot2 dependence chains + barrier convoy. This shape
// halves both latency terms while conserving all throughput terms:
// thread (u = tau&255, j = tau>>8) computes ALL FOUR gates of unit u over
// k-half j. Persist 4x48 = 192 regs (~64 temps left, like R0's 72);
// chains 4 x 64-deep (was 2 x 128); h-broadcast 16 b128/thread (was 32);
// tail 16 b128/thread (was 18). Each SIMD hosts one j=0 and one j=1 wave,
// so the j=0-only epilogue runs on every SIMD. Combine: j=1 writes its 4
// raw partials as one float4; j=0 adds, activates, updates c,h.
// Numerics: one fp32 re-association ((x+sum_k0)+sum_k1); fp16 weight
// quantization dominates.
// ---------------------------------------------------------------------------
__global__ __launch_bounds__(512, 2) void lstm_single_cu(
    const int* __restrict__ ids, const int* __restrict__ lens,
    const float* __restrict__ eproj,
    const u32* __restrict__ wvq, const u32* __restrict__ wlq,
    float* __restrict__ out)
{
    const int b   = blockIdx.x;
    const int tau = threadIdx.x;                 // 0..511
    const int u   = tau & (HID - 1);             // unit
    const int j   = tau >> 8;                    // k-half (wave-uniform)
    const int rI  = u;                           // gate rows of unit u
    const int rF  = 256 + u;
    const int rG  = 512 + u;
    const int rO  = 768 + u;

    __shared__ u32    wl_sh[2 * (KLH / 4) * G4 * 4];  // 8 chunks x 1024 x 16B
    __shared__ u32    h2_sh[2][HID / 2];              // h as half2, parity x2
    __shared__ float4 gs4[HID];                       // j=1 partials bounce
    __shared__ int    id_sh[SEQT];                    // id row (4 KB)

    const int* idr = ids + (size_t)b * SEQT;
    ((int2*)id_sh)[tau] = ((const int2*)idr)[tau];    // 512 x 8B
    if (tau < HID / 2) h2_sh[0][tau] = 0u;            // h(0) = 0

    // stage LDS weight tail (b128 both sides, coalesced): 16 iters, 128 KB
    {
        const uint4* src = (const uint4*)wlq;
        uint4*       dst = (uint4*)wl_sh;
#pragma unroll
        for (int t = 0; t < 2 * (KLH / 4) * G4 / 512; t++)
            dst[t * 512 + tau] = src[t * 512 + tau];
    }

    // persistent weights: 4 gates x 48 h2 = 192 regs (VGPR+AGPR unified)
    u32 wI[KVH], wF[KVH], wG[KVH], wO[KVH];
#pragma unroll
    for (int q = 0; q < KVH / 4; q++) {
        const int ch = j * (KVH / 4) + q;
        uint4 ti = ((const uint4*)wvq)[ch * G4 + rI];
        uint4 tf = ((const uint4*)wvq)[ch * G4 + rF];
        uint4 tg = ((const uint4*)wvq)[ch * G4 + rG];
        uint4 to = ((const uint4*)wvq)[ch * G4 + rO];
        wI[4 * q + 0] = ti.x; wI[4 * q + 1] = ti.y;
        wI[4 * q + 2] = ti.z; wI[4 * q + 3] = ti.w;
        wF[4 * q + 0] = tf.x; wF[4 * q + 1] = tf.y;
        wF[4 * q + 2] = tf.z; wF[4 * q + 3] = tf.w;
        wG[4 * q + 0] = tg.x; wG[4 * q + 1] = tg.y;
        wG[4 * q + 2] = tg.z; wG[4 * q + 3] = tg.w;
        wO[4 * q + 0] = to.x; wO[4 * q + 1] = to.y;
        wO[4 * q + 2] = to.z; wO[4 * q + 3] = to.w;
    }

    const int len = lens[b];                     // >= 1
    float c = 0.f, hf = 0.f;

    // x projections live in the j=0 accumulators only
    float xI = 0.f, xF = 0.f, xG = 0.f, xO = 0.f;
    if (j == 0) {
        const float* e0 = eproj + (size_t)idr[0] * G4;
        xI = e0[rI]; xF = e0[rF]; xG = e0[rG]; xO = e0[rO];
    }

    __syncthreads();

    for (int t = 0; t < len; t++) {
        // prefetch next step's input projections (j=0 only, wave-uniform)
        const int nt = (t + 1 < len) ? t + 1 : len - 1;
        const int nid = id_sh[nt];
        float nI = 0.f, nF = 0.f, nG = 0.f, nO = 0.f;
        if (j == 0) {
            const float* en = eproj + (size_t)nid * G4;
            nI = en[rI]; nF = en[rF]; nG = en[rG]; nO = en[rO];
        }

        const int p = t & 1;
        const uint4* hb4 = (const uint4*)h2_sh[p] + 16 * j;  // this k-half
        float aI = xI, aF = xF, aG = xG, aO = xO;

        // register cols (12 chunks x 16 dots); 4 chains x 64 deep total
#pragma unroll
        for (int q = 0; q < KVH / 4; q++) {
            uint4 h4 = hb4[q];
            aI = fdot2_(wI[4 * q + 0], h4.x, aI);
            aF = fdot2_(wF[4 * q + 0], h4.x, aF);
            aG = fdot2_(wG[4 * q + 0], h4.x, aG);
            aO = fdot2_(wO[4 * q + 0], h4.x, aO);
            aI = fdot2_(wI[4 * q + 1], h4.y, aI);
            aF = fdot2_(wF[4 * q + 1], h4.y, aF);
            aG = fdot2_(wG[4 * q + 1], h4.y, aG);
            aO = fdot2_(wO[4 * q + 1], h4.y, aO);
            aI = fdot2_(wI[4 * q + 2], h4.z, aI);
            aF = fdot2_(wF[4 * q + 2], h4.z, aF);
            aG = fdot2_(wG[4 * q + 2], h4.z, aG);
            aO = fdot2_(wO[4 * q + 2], h4.z, aO);
            aI = fdot2_(wI[4 * q + 3], h4.w, aI);
            aF = fdot2_(wF[4 * q + 3], h4.w, aF);
            aG = fdot2_(wG[4 * q + 3], h4.w, aG);
            aO = fdot2_(wO[4 * q + 3], h4.w, aO);
        }
        // LDS tail (4 chunks; lane-consecutive b128, conflict-free)
#pragma unroll
        for (int q = 0; q < KLH / 4; q++) {
            uint4 h4 = hb4[KVH / 4 + q];
            const int ch = j * (KLH / 4) + q;
            uint4 tI = ((const uint4*)wl_sh)[ch * G4 + rI];
            uint4 tF = ((const uint4*)wl_sh)[ch * G4 + rF];
            uint4 tG = ((const uint4*)wl_sh)[ch * G4 + rG];
            uint4 tO = ((const uint4*)wl_sh)[ch * G4 + rO];
            aI = fdot2_(tI.x, h4.x, aI);
            aF = fdot2_(tF.x, h4.x, aF);
            aG = fdot2_(tG.x, h4.x, aG);
            aO = fdot2_(tO.x, h4.x, aO);
            aI = fdot2_(tI.y, h4.y, aI);
            aF = fdot2_(tF.y, h4.y, aF);
            aG = fdot2_(tG.y, h4.y, aG);
            aO = fdot2_(tO.y, h4.y, aO);
            aI = fdot2_(tI.z, h4.z, aI);
            aF = fdot2_(tF.z, h4.z, aF);
            aG = fdot2_(tG.z, h4.z, aG);
            aO = fdot2_(tO.z, h4.z, aO);
            aI = fdot2_(tI.w, h4.w, aI);
            aF = fdot2_(tF.w, h4.w, aF);
            aG = fdot2_(tG.w, h4.w, aG);
            aO = fdot2_(tO.w, h4.w, aO);
        }

        if (j == 1) {                // publish raw k-half-1 partials (b128)
            gs4[u] = make_float4(aI, aF, aG, aO);
        }
        __syncthreads();             // barrier A: partials visible

        if (j == 0) {                // combine + activate + state update
            float4 pp = gs4[u];
            float ig = sigmoidf_(aI + pp.x);
            float fg = sigmoidf_(aF + pp.y);
            float gg = tanhf_(aG + pp.z);
            float og = sigmoidf_(aO + pp.w);
            c  = fg * c + ig * gg;
            hf = og * tanhf_(c);
            H2U hv; hv.h.x = (f16)hf; hv.h.y = (f16)0.f;
            ((unsigned short*)h2_sh[p ^ 1])[u] = hv.s[0];
        }
        xI = nI; xF = nF; xG = nG; xO = nO;
        __syncthreads();             // barrier B: h(t+1) published
    }

    if (tau < HID) out[(size_t)b * HID + u] = hf;   // j=0 threads hold state
}

// ---------------------------------------------------------------------------
// Fallback (ws too small): correct-but-slow single-block fp32 version.
// ---------------------------------------------------------------------------
__global__ __launch_bounds__(1024, 1) void lstm_fallback(
    const int* __restrict__ ids, const int* __restrict__ lens,
    const float* __restrict__ emb, const float* __restrict__ W_ih,
    const float* __restrict__ b_ih, const float* __restrict__ b_hh,
    const float* __restrict__ W_hh, float* __restrict__ out)
{
    const int b = blockIdx.x;
    const int t = threadIdx.x;

    __shared__ __align__(16) float h_sh[HID];
    __shared__ __align__(16) float c_sh[HID];
    __shared__ __align__(16) float gates[G4];
    __shared__ __align__(16) float x_sh[EMB];

    float wih[EMB];
    {
        const float4* wr = (const float4*)(W_ih + (size_t)t * EMB);
#pragma unroll
        for (int e4 = 0; e4 < EMB / 4; e4++) {
            float4 wv = wr[e4];
            wih[4 * e4 + 0] = wv.x;
            wih[4 * e4 + 1] = wv.y;
            wih[4 * e4 + 2] = wv.z;
            wih[4 * e4 + 3] = wv.w;
        }
    }
    float bias = b_ih[t] + b_hh[t];

    const int len = lens[b];
    const int* ids_row = ids + (size_t)b * SEQT;
    if (t < HID) { h_sh[t] = 0.f; c_sh[t] = 0.f; }
    __syncthreads();

    for (int step = 0; step < len; step++) {
        int id = ids_row[step];
        if (t < EMB / 4) {
            ((float4*)x_sh)[t] = ((const float4*)(emb + (size_t)id * EMB))[t];
        }
        __syncthreads();
        float a0 = bias, a1 = 0.f, a2 = 0.f, a3 = 0.f;
#pragma unroll
        for (int e4 = 0; e4 < EMB / 4; e4++) {
            float4 xv = ((const float4*)x_sh)[e4];
            a0 += wih[4 * e4 + 0] * xv.x;
            a1 += wih[4 * e4 + 1] * xv.y;
            a2 += wih[4 * e4 + 2] * xv.z;
            a3 += wih[4 * e4 + 3] * xv.w;
        }
        float acc = (a0 + a1) + (a2 + a3);

        const float* wrow = W_hh + (size_t)t * HID;
        a0 = acc; a1 = 0.f; a2 = 0.f; a3 = 0.f;
        for (int k4 = 0; k4 < HID / 4; k4++) {
            float4 hv = ((const float4*)h_sh)[k4];
            float4 wv = ((const float4*)wrow)[k4];
            a0 += wv.x * hv.x;
            a1 += wv.y * hv.y;
            a2 += wv.z * hv.z;
            a3 += wv.w * hv.w;
        }
        gates[t] = (a0 + a1) + (a2 + a3);
        __syncthreads();

        if (t < HID) {
            float ig = sigmoidf_(gates[t]);
            float fg = sigmoidf_(gates[HID + t]);
            float gg = tanhf_(gates[2 * HID + t]);
            float og = sigmoidf_(gates[3 * HID + t]);
            float cc = fg * c_sh[t] + ig * gg;
            c_sh[t] = cc;
            h_sh[t] = og * tanhf_(cc);
        }
        __syncthreads();
    }
    if (t < HID) out[(size_t)b * HID + t] = h_sh[t];
}

extern "C" void kernel_launch(void* const* d_in, const int* in_sizes, int n_in,
                              void* d_out, int out_size, void* d_ws, size_t ws_size,
                              hipStream_t stream) {
    const int*   ids  = (const int*)d_in[0];
    const int*   lens = (const int*)d_in[1];
    const float* emb  = (const float*)d_in[2];
    const float* Wih  = (const float*)d_in[3];
    const float* Whh  = (const float*)d_in[4];
    const float* bih  = (const float*)d_in[5];
    const float* bhh  = (const float*)d_in[6];
    float* out = (float*)d_out;

    // ws layout: eproj 4 MB | wvq 384 KB | wlq 128 KB
    const size_t ep_bytes = (size_t)VOCAB * G4 * sizeof(float);
    const size_t wv_off   = ep_bytes;
    const size_t wv_bytes = (size_t)2 * (KVH / 4) * G4 * 4 * sizeof(u32);
    const size_t wl_off   = wv_off + wv_bytes;
    const size_t wl_bytes = (size_t)2 * (KLH / 4) * G4 * 4 * sizeof(u32);

    if (ws_size >= wl_off + wl_bytes) {
        float* eproj = (float*)d_ws;
        u32*   wvp   = (u32*)((char*)d_ws + wv_off);
        u32*   wlp   = (u32*)((char*)d_ws + wl_off);
        eproj_kernel<<<VOCAB, 1024, 0, stream>>>(emb, Wih, bih, bhh, eproj);
        pack_whh<<<G4, 128, 0, stream>>>(Whh, wvp, wlp);
        lstm_single_cu<<<BATCH, 512, 0, stream>>>(ids, lens, eproj, wvp, wlp, out);
    } else {
        lstm_fallback<<<BATCH, 1024, 0, stream>>>(
            ids, lens, emb, Wih, bih, bhh, Whh, out);
    }
}